// Round 4
// baseline (13407.118 us; speedup 1.0000x reference)
//
#include <hip/hip_runtime.h>
#include <hip/hip_bf16.h>

#define N_NODES 100000
#define N_EDGES 1600000
#define HID 128

// monotonic float<->uint mapping for atomicMax on signed floats
__device__ __forceinline__ unsigned int fenc(float f) {
    unsigned int u = __float_as_uint(f);
    return (u & 0x80000000u) ? ~u : (u | 0x80000000u);
}
__device__ __forceinline__ float fdec(unsigned int u) {
    unsigned int b = (u & 0x80000000u) ? (u ^ 0x80000000u) : ~u;
    return __uint_as_float(b);
}

// ---------------- fused node GEMM: q,k,v,skip = X @ {Wq,Wk,Wv,Ws} + b ---------
// also (re)initializes m, s, agg for the layer.
template<int DIN>
__global__ __launch_bounds__(128)
void node_linear(const float* __restrict__ X,
                 const float* __restrict__ Wq, const float* __restrict__ Wk,
                 const float* __restrict__ Wv, const float* __restrict__ Ws,
                 const float* __restrict__ bq, const float* __restrict__ bk,
                 const float* __restrict__ bv, const float* __restrict__ bs,
                 float* __restrict__ q, float* __restrict__ k, float* __restrict__ v,
                 float* __restrict__ skp, float* __restrict__ agg,
                 unsigned int* __restrict__ mbuf, float* __restrict__ sbuf)
{
    const int t = threadIdx.x;              // 0..127 = output column
    const int n0 = blockIdx.x * 8;
    __shared__ float xs[8][DIN];
    for (int n = 0; n < 8; ++n) {
        int node = n0 + n;
        for (int j = t; j < DIN; j += 128) {
            xs[n][j] = (node < N_NODES) ? X[(long)node * DIN + j] : 0.f;
        }
    }
    __syncthreads();
    float aq[8] = {}, ak[8] = {}, av[8] = {}, as_[8] = {};
    for (int j = 0; j < DIN; ++j) {
        float wq = Wq[j * HID + t];
        float wk = Wk[j * HID + t];
        float wv = Wv[j * HID + t];
        float ws = Ws[j * HID + t];
#pragma unroll
        for (int n = 0; n < 8; ++n) {
            float xv = xs[n][j];
            aq[n] = fmaf(xv, wq, aq[n]);
            ak[n] = fmaf(xv, wk, ak[n]);
            av[n] = fmaf(xv, wv, av[n]);
            as_[n] = fmaf(xv, ws, as_[n]);
        }
    }
    float bqv = bq[t], bkv = bk[t], bvv = bv[t], bsv = bs[t];
    for (int n = 0; n < 8; ++n) {
        int node = n0 + n;
        if (node < N_NODES) {
            q[(long)node * HID + t]   = aq[n] + bqv;
            k[(long)node * HID + t]   = ak[n] + bkv;
            v[(long)node * HID + t]   = av[n] + bvv;
            skp[(long)node * HID + t] = as_[n] + bsv;
            agg[(long)node * HID + t] = 0.f;
            if (t < 4) { mbuf[node * 4 + t] = 0u; sbuf[node * 4 + t] = 0.f; }
        }
    }
}

// ---------------- pass 1: alpha + segment max --------------------------------
__global__ __launch_bounds__(256)
void edge_alpha(const float* __restrict__ EA, const float* __restrict__ WE,
                const int* __restrict__ esrc, const int* __restrict__ edst,
                const float* __restrict__ q, const float* __restrict__ k,
                float* __restrict__ alpha, unsigned int* __restrict__ mbuf)
{
    const int wid  = threadIdx.x >> 6;
    const int lane = threadIdx.x & 63;
    const int e    = blockIdx.x * 4 + wid;
    const bool valid = (e < N_EDGES);
    __shared__ float eas[4][64];
    int src = 0, dst = 0;
    if (valid) { src = esrc[e]; dst = edst[e]; }
    eas[wid][lane] = valid ? EA[(long)e * 64 + lane] : 0.f;
    __syncthreads();
    const int c0 = lane * 2;
    float e0 = 0.f, e1 = 0.f;
#pragma unroll 8
    for (int j = 0; j < 64; ++j) {
        float eaj = eas[wid][j];
        float2 wp = *(const float2*)(WE + j * HID + c0);
        e0 = fmaf(eaj, wp.x, e0);
        e1 = fmaf(eaj, wp.y, e1);
    }
    float2 kf = *(const float2*)(k + (long)src * HID + c0);
    float2 qf = *(const float2*)(q + (long)dst * HID + c0);
    float p = qf.x * (kf.x + e0) + qf.y * (kf.y + e1);
    p += __shfl_xor(p, 1);
    p += __shfl_xor(p, 2);
    p += __shfl_xor(p, 4);
    p += __shfl_xor(p, 8);
    if (valid && (lane & 15) == 0) {
        int h = lane >> 4;
        float a = p * 0.17677669529663689f;   // 1/sqrt(32)
        alpha[(long)e * 4 + h] = a;
        atomicMax(mbuf + (long)dst * 4 + h, fenc(a));
    }
}

// ---------------- pass 2: exp, segment sum, weighted aggregate ---------------
__global__ __launch_bounds__(256)
void edge_agg(const float* __restrict__ EA, const float* __restrict__ WE,
              const int* __restrict__ esrc, const int* __restrict__ edst,
              const float* __restrict__ v, const float* __restrict__ alpha,
              const unsigned int* __restrict__ mbuf, float* __restrict__ sbuf,
              float* __restrict__ agg)
{
    const int wid  = threadIdx.x >> 6;
    const int lane = threadIdx.x & 63;
    const int e    = blockIdx.x * 4 + wid;
    const bool valid = (e < N_EDGES);
    __shared__ float eas[4][64];
    int src = 0, dst = 0;
    if (valid) { src = esrc[e]; dst = edst[e]; }
    eas[wid][lane] = valid ? EA[(long)e * 64 + lane] : 0.f;
    __syncthreads();
    const int c0 = lane * 2;
    float e0 = 0.f, e1 = 0.f;
#pragma unroll 8
    for (int j = 0; j < 64; ++j) {
        float eaj = eas[wid][j];
        float2 wp = *(const float2*)(WE + j * HID + c0);
        e0 = fmaf(eaj, wp.x, e0);
        e1 = fmaf(eaj, wp.y, e1);
    }
    float2 vf = *(const float2*)(v + (long)src * HID + c0);
    float v0 = vf.x + e0;
    float v1 = vf.y + e1;
    const int h = lane >> 4;
    if (valid) {
        float mval = fdec(mbuf[(long)dst * 4 + h]);
        float a = __expf(alpha[(long)e * 4 + h] - mval);
        if ((lane & 15) == 0) atomicAdd(sbuf + (long)dst * 4 + h, a);
        atomicAdd(agg + (long)dst * HID + c0,     a * v0);
        atomicAdd(agg + (long)dst * HID + c0 + 1, a * v1);
    }
}

// ---------------- finalize: normalize + skip (+ relu) ------------------------
template<bool RELU>
__global__ __launch_bounds__(256)
void finalize_k(const float* __restrict__ agg, const float* __restrict__ sbuf,
                const float* __restrict__ skp, float* __restrict__ out)
{
    long idx = (long)blockIdx.x * 256 + threadIdx.x;
    if (idx >= (long)N_NODES * HID) return;
    int col = (int)(idx & (HID - 1));
    long n  = idx >> 7;
    int h   = col >> 5;
    float val = agg[idx] / fmaxf(sbuf[n * 4 + h], 1e-16f) + skp[idx];
    if (RELU) val = fmaxf(val, 0.f);
    out[idx] = val;
}

extern "C" void kernel_launch(void* const* d_in, const int* in_sizes, int n_in,
                              void* d_out, int out_size, void* d_ws, size_t ws_size,
                              hipStream_t stream)
{
    const float* x   = (const float*)d_in[0];
    const int*   ei  = (const int*)d_in[1];
    const float* ea  = (const float*)d_in[2];
    const float* wq1 = (const float*)d_in[3];
    const float* bq1 = (const float*)d_in[4];
    const float* wk1 = (const float*)d_in[5];
    const float* bk1 = (const float*)d_in[6];
    const float* wv1 = (const float*)d_in[7];
    const float* bv1 = (const float*)d_in[8];
    const float* we1 = (const float*)d_in[9];
    const float* ws1 = (const float*)d_in[10];
    const float* bs1 = (const float*)d_in[11];
    const float* wq2 = (const float*)d_in[12];
    const float* bq2 = (const float*)d_in[13];
    const float* wk2 = (const float*)d_in[14];
    const float* bk2 = (const float*)d_in[15];
    const float* wv2 = (const float*)d_in[16];
    const float* bv2 = (const float*)d_in[17];
    const float* we2 = (const float*)d_in[18];
    const float* ws2 = (const float*)d_in[19];
    const float* bs2 = (const float*)d_in[20];

    const int* esrc = ei;
    const int* edst = ei + N_EDGES;

    char* ws = (char*)d_ws;
    size_t off = 0;
    auto carve = [&](size_t bytes) {
        void* p = ws + off;
        off += (bytes + 255) & ~(size_t)255;
        return p;
    };
    float*        q    = (float*)carve((size_t)N_NODES * HID * 4);
    float*        k    = (float*)carve((size_t)N_NODES * HID * 4);
    float*        v    = (float*)carve((size_t)N_NODES * HID * 4);
    float*        skp  = (float*)carve((size_t)N_NODES * HID * 4);
    float*        agg  = (float*)carve((size_t)N_NODES * HID * 4);
    float*        hbuf = (float*)carve((size_t)N_NODES * HID * 4);
    float*        alph = (float*)carve((size_t)N_EDGES * 4 * 4);
    unsigned int* mbuf = (unsigned int*)carve((size_t)N_NODES * 4 * 4);
    float*        sbuf = (float*)carve((size_t)N_NODES * 4 * 4);

    const int nl_grid = (N_NODES + 7) / 8;
    const int eg_grid = (N_EDGES + 3) / 4;
    const int fin_grid = (int)(((long)N_NODES * HID + 255) / 256);

    // ---------------- layer 1 ----------------
    node_linear<256><<<nl_grid, 128, 0, stream>>>(
        x, wq1, wk1, wv1, ws1, bq1, bk1, bv1, bs1, q, k, v, skp, agg, mbuf, sbuf);
    edge_alpha<<<eg_grid, 256, 0, stream>>>(ea, we1, esrc, edst, q, k, alph, mbuf);
    edge_agg<<<eg_grid, 256, 0, stream>>>(ea, we1, esrc, edst, v, alph, mbuf, sbuf, agg);
    finalize_k<true><<<fin_grid, 256, 0, stream>>>(agg, sbuf, skp, hbuf);

    // ---------------- layer 2 ----------------
    node_linear<128><<<nl_grid, 128, 0, stream>>>(
        hbuf, wq2, wk2, wv2, ws2, bq2, bk2, bv2, bs2, q, k, v, skp, agg, mbuf, sbuf);
    edge_alpha<<<eg_grid, 256, 0, stream>>>(ea, we2, esrc, edst, q, k, alph, mbuf);
    edge_agg<<<eg_grid, 256, 0, stream>>>(ea, we2, esrc, edst, v, alph, mbuf, sbuf, agg);
    finalize_k<false><<<fin_grid, 256, 0, stream>>>(agg, sbuf, skp, (float*)d_out);
}

// Round 5
// 4060.089 us; speedup vs baseline: 3.3022x; 3.3022x over previous
//
#include <hip/hip_runtime.h>
#include <hip/hip_bf16.h>

#define N_NODES 100000
#define N_EDGES 1600000
#define HID 128
#define SCAN_B ((N_NODES + 255) / 256)   // 391 blocks

// ---------------- fused node GEMM: q,k,v,skip = X @ {Wq,Wk,Wv,Ws} + b ---------
template<int DIN>
__global__ __launch_bounds__(128)
void node_linear(const float* __restrict__ X,
                 const float* __restrict__ Wq, const float* __restrict__ Wk,
                 const float* __restrict__ Wv, const float* __restrict__ Ws,
                 const float* __restrict__ bq, const float* __restrict__ bk,
                 const float* __restrict__ bv, const float* __restrict__ bs,
                 float* __restrict__ q, float* __restrict__ k, float* __restrict__ v,
                 float* __restrict__ skp)
{
    const int t = threadIdx.x;              // 0..127 = output column
    const int n0 = blockIdx.x * 8;
    __shared__ float xs[8][DIN];
    for (int n = 0; n < 8; ++n) {
        int node = n0 + n;
        for (int j = t; j < DIN; j += 128) {
            xs[n][j] = (node < N_NODES) ? X[(long)node * DIN + j] : 0.f;
        }
    }
    __syncthreads();
    float aq[8] = {}, ak[8] = {}, av[8] = {}, as_[8] = {};
    for (int j = 0; j < DIN; ++j) {
        float wq = Wq[j * HID + t];
        float wk = Wk[j * HID + t];
        float wv = Wv[j * HID + t];
        float ws = Ws[j * HID + t];
#pragma unroll
        for (int n = 0; n < 8; ++n) {
            float xv = xs[n][j];
            aq[n] = fmaf(xv, wq, aq[n]);
            ak[n] = fmaf(xv, wk, ak[n]);
            av[n] = fmaf(xv, wv, av[n]);
            as_[n] = fmaf(xv, ws, as_[n]);
        }
    }
    float bqv = bq[t], bkv = bk[t], bvv = bv[t], bsv = bs[t];
    for (int n = 0; n < 8; ++n) {
        int node = n0 + n;
        if (node < N_NODES) {
            q[(long)node * HID + t]   = aq[n] + bqv;
            k[(long)node * HID + t]   = ak[n] + bkv;
            v[(long)node * HID + t]   = av[n] + bvv;
            skp[(long)node * HID + t] = as_[n] + bsv;
        }
    }
}

// ---------------- CSR build: counts -> exclusive scan -> scatter -------------
__global__ __launch_bounds__(256) void zero_counts(int* __restrict__ c) {
    int i = blockIdx.x * 256 + threadIdx.x;
    if (i < N_NODES) c[i] = 0;
}
__global__ __launch_bounds__(256) void hist_k(const int* __restrict__ edst, int* __restrict__ c) {
    for (int e = blockIdx.x * 256 + threadIdx.x; e < N_EDGES; e += gridDim.x * 256)
        atomicAdd(&c[edst[e]], 1);
}
__global__ __launch_bounds__(256)
void scan1(const int* __restrict__ c, int* __restrict__ offs, int* __restrict__ bsum) {
    __shared__ int sd[256];
    int i = blockIdx.x * 256 + threadIdx.x;
    int val = (i < N_NODES) ? c[i] : 0;
    sd[threadIdx.x] = val; __syncthreads();
    for (int d = 1; d < 256; d <<= 1) {
        int t = (threadIdx.x >= d) ? sd[threadIdx.x - d] : 0;
        __syncthreads();
        sd[threadIdx.x] += t;
        __syncthreads();
    }
    if (i < N_NODES) offs[i] = sd[threadIdx.x] - val;   // block-local exclusive
    if (threadIdx.x == 255) bsum[blockIdx.x] = sd[255];
}
__global__ __launch_bounds__(512) void scan2(int* __restrict__ bsum) {
    __shared__ int sd[512];
    int i = threadIdx.x;
    int val = (i < SCAN_B) ? bsum[i] : 0;
    sd[i] = val; __syncthreads();
    for (int d = 1; d < 512; d <<= 1) {
        int t = (i >= d) ? sd[i - d] : 0;
        __syncthreads();
        sd[i] += t;
        __syncthreads();
    }
    if (i < SCAN_B) bsum[i] = sd[i] - val;              // exclusive
}
__global__ __launch_bounds__(256) void scan3(int* __restrict__ offs, const int* __restrict__ bsum) {
    int i = blockIdx.x * 256 + threadIdx.x;
    if (i < N_NODES) offs[i] += bsum[blockIdx.x];
}
// after scatter, offs[n] == end of row n; start of row n == (n? offs[n-1] : 0)
__global__ __launch_bounds__(256)
void scatter_k(const int* __restrict__ edst, int* __restrict__ offs, int* __restrict__ csr) {
    for (int e = blockIdx.x * 256 + threadIdx.x; e < N_EDGES; e += gridDim.x * 256) {
        int pos = atomicAdd(&offs[edst[e]], 1);
        csr[pos] = e;
    }
}

// ---------------- fused per-dst attention: online softmax, no atomics --------
// 1 wave per dst node; lane owns cols {2*lane, 2*lane+1}; head = lane>>4.
// WE columns held in registers; EA row broadcast via shfl (no LDS, no barrier),
// so next-edge loads (csr/esrc/EA) prefetch under the 128-FMA e-compute.
template<bool RELU>
__global__ __launch_bounds__(64)
void fused_attn(const int* __restrict__ offs, const int* __restrict__ csr,
                const int* __restrict__ esrc,
                const float* __restrict__ EA, const float* __restrict__ WE,
                const float* __restrict__ q, const float* __restrict__ k,
                const float* __restrict__ v, const float* __restrict__ skp,
                float* __restrict__ out)
{
    const int n = blockIdx.x;
    const int lane = threadIdx.x;
    const int c0 = lane * 2;
    float wx[64], wy[64];
#pragma unroll
    for (int j = 0; j < 64; ++j) {
        float2 w = *(const float2*)(WE + j * HID + c0);
        wx[j] = w.x; wy[j] = w.y;
    }
    float2 qf = *(const float2*)(q + (long)n * HID + c0);
    const int e_beg = (n == 0) ? 0 : offs[n - 1];
    const int e_end = offs[n];
    float m = -INFINITY, s = 0.f, a0 = 0.f, a1 = 0.f;
    int src = 0; float eav = 0.f;
    if (e_beg < e_end) {
        int eid = csr[e_beg];
        src = esrc[eid];
        eav = EA[(long)eid * 64 + lane];
    }
    for (int i = e_beg; i < e_end; ++i) {
        float2 kf = *(const float2*)(k + (long)src * HID + c0);
        float2 vf = *(const float2*)(v + (long)src * HID + c0);
        float ecur = eav;
        int srcn = 0; float eavn = 0.f;
        if (i + 1 < e_end) {                  // wave-uniform branch; prefetch next edge
            int eid2 = csr[i + 1];
            srcn = esrc[eid2];
            eavn = EA[(long)eid2 * 64 + lane];
        }
        float e0 = 0.f, e1 = 0.f;
#pragma unroll
        for (int j = 0; j < 64; ++j) {
            float ej = __shfl(ecur, j);
            e0 = fmaf(ej, wx[j], e0);
            e1 = fmaf(ej, wy[j], e1);
        }
        src = srcn; eav = eavn;
        float p = qf.x * (kf.x + e0) + qf.y * (kf.y + e1);
        p += __shfl_xor(p, 1);
        p += __shfl_xor(p, 2);
        p += __shfl_xor(p, 4);
        p += __shfl_xor(p, 8);                // 16-lane head reduce
        float al = p * 0.17677669529663689f;  // 1/sqrt(32)
        float mn = fmaxf(m, al);
        float sc = __expf(m - mn);            // first iter: exp(-inf)=0
        float w8 = __expf(al - mn);
        s  = s * sc + w8;
        a0 = a0 * sc + w8 * (vf.x + e0);
        a1 = a1 * sc + w8 * (vf.y + e1);
        m = mn;
    }
    float inv = 1.f / fmaxf(s, 1e-16f);
    float2 sk = *(const float2*)(skp + (long)n * HID + c0);
    float o0 = fmaf(a0, inv, sk.x);
    float o1 = fmaf(a1, inv, sk.y);
    if (RELU) { o0 = fmaxf(o0, 0.f); o1 = fmaxf(o1, 0.f); }
    float2 ov = make_float2(o0, o1);
    *(float2*)(out + (long)n * HID + c0) = ov;
}

extern "C" void kernel_launch(void* const* d_in, const int* in_sizes, int n_in,
                              void* d_out, int out_size, void* d_ws, size_t ws_size,
                              hipStream_t stream)
{
    const float* x   = (const float*)d_in[0];
    const int*   ei  = (const int*)d_in[1];
    const float* ea  = (const float*)d_in[2];
    const float* wq1 = (const float*)d_in[3];
    const float* bq1 = (const float*)d_in[4];
    const float* wk1 = (const float*)d_in[5];
    const float* bk1 = (const float*)d_in[6];
    const float* wv1 = (const float*)d_in[7];
    const float* bv1 = (const float*)d_in[8];
    const float* we1 = (const float*)d_in[9];
    const float* ws1 = (const float*)d_in[10];
    const float* bs1 = (const float*)d_in[11];
    const float* wq2 = (const float*)d_in[12];
    const float* bq2 = (const float*)d_in[13];
    const float* wk2 = (const float*)d_in[14];
    const float* bk2 = (const float*)d_in[15];
    const float* wv2 = (const float*)d_in[16];
    const float* bv2 = (const float*)d_in[17];
    const float* we2 = (const float*)d_in[18];
    const float* ws2 = (const float*)d_in[19];
    const float* bs2 = (const float*)d_in[20];

    const int* esrc = ei;
    const int* edst = ei + N_EDGES;

    char* ws = (char*)d_ws;
    size_t off = 0;
    auto carve = [&](size_t bytes) {
        void* p = ws + off;
        off += (bytes + 255) & ~(size_t)255;
        return p;
    };
    float* q    = (float*)carve((size_t)N_NODES * HID * 4);
    float* k    = (float*)carve((size_t)N_NODES * HID * 4);
    float* v    = (float*)carve((size_t)N_NODES * HID * 4);
    float* skp  = (float*)carve((size_t)N_NODES * HID * 4);
    float* hbuf = (float*)carve((size_t)N_NODES * HID * 4);
    int*   cnts = (int*)carve((size_t)N_NODES * 4);
    int*   offs = (int*)carve((size_t)N_NODES * 4);
    int*   bsum = (int*)carve((size_t)SCAN_B * 4);
    int*   csr  = (int*)carve((size_t)N_EDGES * 4);

    const int nl_grid = (N_NODES + 7) / 8;

    // ---------------- CSR build (graph is shared by both layers) -------------
    zero_counts<<<SCAN_B, 256, 0, stream>>>(cnts);
    hist_k<<<2048, 256, 0, stream>>>(edst, cnts);
    scan1<<<SCAN_B, 256, 0, stream>>>(cnts, offs, bsum);
    scan2<<<1, 512, 0, stream>>>(bsum);
    scan3<<<SCAN_B, 256, 0, stream>>>(offs, bsum);
    scatter_k<<<2048, 256, 0, stream>>>(edst, offs, csr);

    // ---------------- layer 1 ----------------
    node_linear<256><<<nl_grid, 128, 0, stream>>>(
        x, wq1, wk1, wv1, ws1, bq1, bk1, bv1, bs1, q, k, v, skp);
    fused_attn<true><<<N_NODES, 64, 0, stream>>>(
        offs, csr, esrc, ea, we1, q, k, v, skp, hbuf);

    // ---------------- layer 2 ----------------
    node_linear<128><<<nl_grid, 128, 0, stream>>>(
        hbuf, wq2, wk2, wv2, ws2, bq2, bk2, bv2, bs2, q, k, v, skp);
    fused_attn<false><<<N_NODES, 64, 0, stream>>>(
        offs, csr, esrc, ea, we2, q, k, v, skp, (float*)d_out);
}